// Round 1
// baseline (2104.491 us; speedup 1.0000x reference)
//
#include <hip/hip_runtime.h>

#define DIM 64
#define NEG 0.01f

// --- degree count: deg[d] += 1 per edge ---
__global__ void k_deg(const int* __restrict__ dst, int E, float* __restrict__ deg) {
    int i = blockIdx.x * blockDim.x + threadIdx.x;
    int stride = gridDim.x * blockDim.x;
    for (int e = i; e < E; e += stride) atomicAdd(&deg[dst[e]], 1.0f);
}

// --- dinv[i] = rsqrt(deg[i] + 1) (self-loop) ---
__global__ void k_dinv(float* __restrict__ deg, int N) {
    int i = blockIdx.x * blockDim.x + threadIdx.x;
    if (i < N) deg[i] = rsqrtf(deg[i] + 1.0f);
}

// --- h = x @ W  (x: N x xstride row-major, using first 64 cols; W: 64x64) ---
__global__ void k_linear(const float* __restrict__ x, int xstride,
                         const float* __restrict__ W,
                         float* __restrict__ h, int N) {
    __shared__ float Ws[DIM][DIM];
    int t = threadIdx.x;
#pragma unroll
    for (int k = 0; k < 16; ++k) {
        int idx = t + k * 256;
        Ws[idx >> 6][idx & 63] = W[idx];
    }
    __syncthreads();
    int row = blockIdx.x * 4 + (t >> 6);
    int col = t & 63;
    if (row >= N) return;
    const float* xr = x + (size_t)row * xstride;
    float acc = 0.f;
#pragma unroll
    for (int k = 0; k < DIM; ++k) acc = fmaf(xr[k], Ws[k][col], acc);
    h[(size_t)row * DIM + col] = acc;
}

// --- scatter: agg[dst] += h[src] * dinv[src]*dinv[dst], one wave per edge ---
__global__ void k_scatter(const int* __restrict__ src, const int* __restrict__ dst,
                          const float* __restrict__ h, const float* __restrict__ dinv,
                          float* __restrict__ agg, int E) {
    int wid = blockIdx.x * (blockDim.x >> 6) + (threadIdx.x >> 6);
    int lane = threadIdx.x & 63;
    int nw = gridDim.x * (blockDim.x >> 6);
    for (int e = wid; e < E; e += nw) {
        int s = src[e];
        int d = dst[e];
        float nrm = dinv[s] * dinv[d];
        float v = h[(size_t)s * DIM + lane] * nrm;
        atomicAdd(&agg[(size_t)d * DIM + lane], v);
    }
}

// --- combine: out[i, colOff+j] = leaky_relu(agg + h*dinv^2 + b) ---
__global__ void k_combine(const float* __restrict__ agg, const float* __restrict__ h,
                          const float* __restrict__ dinv, const float* __restrict__ b,
                          float* __restrict__ out, int colOff, int N) {
    int i = blockIdx.x * 4 + (threadIdx.x >> 6);
    int j = threadIdx.x & 63;
    if (i >= N) return;
    float di = dinv[i];
    float v = agg[(size_t)i * DIM + j] + h[(size_t)i * DIM + j] * di * di + b[j];
    v = v > 0.f ? v : v * NEG;
    out[(size_t)i * 128 + colOff + j] = v;
}

extern "C" void kernel_launch(void* const* d_in, const int* in_sizes, int n_in,
                              void* d_out, int out_size, void* d_ws, size_t ws_size,
                              hipStream_t stream) {
    const int* edge = (const int*)d_in[0];
    const float* x0 = (const float*)d_in[1];
    const float* W1 = (const float*)d_in[2];
    const float* b1 = (const float*)d_in[3];
    const float* W2 = (const float*)d_in[4];
    const float* b2 = (const float*)d_in[5];
    float* out = (float*)d_out;

    int E = in_sizes[0] / 2;
    int N = in_sizes[1] / DIM;
    const int* src = edge;       // edge_index[0]
    const int* dst = edge + E;   // edge_index[1]

    // workspace layout: dinv (N), h (N*64), agg (N*64)
    float* dinv = (float*)d_ws;
    size_t off = ((size_t)N * sizeof(float) + 255) & ~(size_t)255;
    float* h = (float*)((char*)d_ws + off);
    float* agg = h + (size_t)N * DIM;

    int nrow_blocks = (N + 3) / 4;

    hipMemsetAsync(dinv, 0, (size_t)N * sizeof(float), stream);
    k_deg<<<2048, 256, 0, stream>>>(dst, E, dinv);
    k_dinv<<<(N + 255) / 256, 256, 0, stream>>>(dinv, N);

    // ---- layer 1 ----
    k_linear<<<nrow_blocks, 256, 0, stream>>>(x0, DIM, W1, h, N);
    hipMemsetAsync(agg, 0, (size_t)N * DIM * sizeof(float), stream);
    k_scatter<<<8192, 256, 0, stream>>>(src, dst, h, dinv, agg, E);
    k_combine<<<nrow_blocks, 256, 0, stream>>>(agg, h, dinv, b1, out, 0, N);

    // ---- layer 2 (x1 read from out, stride 128) ----
    k_linear<<<nrow_blocks, 256, 0, stream>>>(out, 128, W2, h, N);
    hipMemsetAsync(agg, 0, (size_t)N * DIM * sizeof(float), stream);
    k_scatter<<<8192, 256, 0, stream>>>(src, dst, h, dinv, agg, E);
    k_combine<<<nrow_blocks, 256, 0, stream>>>(agg, h, dinv, b2, out, 64, N);
}

// Round 2
// 922.024 us; speedup vs baseline: 2.2825x; 2.2825x over previous
//
#include <hip/hip_runtime.h>

#define DIM 64
#define NEG 0.01f

// --- int histogram of dst ---
__global__ void k_hist(const int* __restrict__ dst, int E, int* __restrict__ cnt) {
    int i = blockIdx.x * blockDim.x + threadIdx.x;
    int stride = gridDim.x * blockDim.x;
    for (int e = i; e < E; e += stride) atomicAdd(&cnt[dst[e]], 1);
}

// --- dinv[i] = rsqrt(cnt[i] + 1) ---
__global__ void k_dinv(const int* __restrict__ cnt, float* __restrict__ dinv, int N) {
    int i = blockIdx.x * blockDim.x + threadIdx.x;
    if (i < N) dinv[i] = rsqrtf((float)cnt[i] + 1.0f);
}

// --- per-256-block sums of cnt ---
__global__ void k_bsum(const int* __restrict__ cnt, int N, int* __restrict__ bsum) {
    int i = blockIdx.x * 256 + threadIdx.x;
    int v = (i < N) ? cnt[i] : 0;
#pragma unroll
    for (int o = 32; o > 0; o >>= 1) v += __shfl_down(v, o);
    __shared__ int s[4];
    if ((threadIdx.x & 63) == 0) s[threadIdx.x >> 6] = v;
    __syncthreads();
    if (threadIdx.x == 0) bsum[blockIdx.x] = s[0] + s[1] + s[2] + s[3];
}

// --- exclusive scan of bsum (nb <= 1024), single block ---
__global__ void k_scan_bsum(int* __restrict__ bsum, int nb) {
    __shared__ int s[1024];
    int t = threadIdx.x;
    int v = (t < nb) ? bsum[t] : 0;
    s[t] = v;
    __syncthreads();
    for (int o = 1; o < 1024; o <<= 1) {
        int u = (t >= o) ? s[t - o] : 0;
        __syncthreads();
        s[t] += u;
        __syncthreads();
    }
    if (t < nb) bsum[t] = s[t] - v;
}

// --- rowptr[i] = bsum[block] + exclusive scan within block ---
__global__ void k_rowptr(const int* __restrict__ cnt, const int* __restrict__ bsum,
                         int N, int* __restrict__ rowptr) {
    __shared__ int s[256];
    int t = threadIdx.x;
    int i = blockIdx.x * 256 + t;
    int v = (i < N) ? cnt[i] : 0;
    s[t] = v;
    __syncthreads();
    for (int o = 1; o < 256; o <<= 1) {
        int u = (t >= o) ? s[t - o] : 0;
        __syncthreads();
        s[t] += u;
        __syncthreads();
    }
    if (i < N) rowptr[i] = bsum[blockIdx.x] + s[t] - v;
}

// --- place edges into CSR order by dst ---
__global__ void k_place(const int* __restrict__ src, const int* __restrict__ dst,
                        const int* __restrict__ rowptr, int* __restrict__ cursor,
                        int* __restrict__ csr_src, int E) {
    int i = blockIdx.x * blockDim.x + threadIdx.x;
    int stride = gridDim.x * blockDim.x;
    for (int e = i; e < E; e += stride) {
        int d = dst[e];
        int pos = atomicAdd(&cursor[d], 1);
        csr_src[rowptr[d] + pos] = src[e];
    }
}

// --- hh = (x @ W) * dinv[row] ---
__global__ void k_linear(const float* __restrict__ x, int xstride,
                         const float* __restrict__ W, const float* __restrict__ dinv,
                         float* __restrict__ hh, int N) {
    __shared__ float Ws[DIM][DIM];
    int t = threadIdx.x;
#pragma unroll
    for (int k = 0; k < 16; ++k) {
        int idx = t + k * 256;
        Ws[idx >> 6][idx & 63] = W[idx];
    }
    __syncthreads();
    int row = blockIdx.x * 4 + (t >> 6);
    int col = t & 63;
    if (row >= N) return;
    const float* xr = x + (size_t)row * xstride;
    float acc = 0.f;
#pragma unroll
    for (int k = 0; k < DIM; ++k) acc = fmaf(xr[k], Ws[k][col], acc);
    hh[(size_t)row * DIM + col] = acc * dinv[row];
}

// --- gather: out[d] = leaky( dinv[d]*(hh[d] + sum hh[src]) + b ), one wave/node ---
__global__ void k_gather(const int* __restrict__ rowptr, const int* __restrict__ cnt,
                         const int* __restrict__ csr_src, const float* __restrict__ hh,
                         const float* __restrict__ dinv, const float* __restrict__ bias,
                         float* __restrict__ out, int colOff, int N) {
    int node = blockIdx.x * (blockDim.x >> 6) + (threadIdx.x >> 6);
    int lane = threadIdx.x & 63;
    if (node >= N) return;
    int beg = rowptr[node];
    int end = beg + cnt[node];
    float acc = hh[(size_t)node * DIM + lane];  // self-loop (hh = h*dinv)
    int k = beg;
    for (; k + 3 < end; k += 4) {
        int s0 = csr_src[k], s1 = csr_src[k + 1], s2 = csr_src[k + 2], s3 = csr_src[k + 3];
        float v0 = hh[(size_t)s0 * DIM + lane];
        float v1 = hh[(size_t)s1 * DIM + lane];
        float v2 = hh[(size_t)s2 * DIM + lane];
        float v3 = hh[(size_t)s3 * DIM + lane];
        acc += (v0 + v1) + (v2 + v3);
    }
    for (; k < end; ++k) acc += hh[(size_t)csr_src[k] * DIM + lane];
    float v = acc * dinv[node] + bias[lane];
    out[(size_t)node * 128 + colOff + lane] = v > 0.f ? v : v * NEG;
}

extern "C" void kernel_launch(void* const* d_in, const int* in_sizes, int n_in,
                              void* d_out, int out_size, void* d_ws, size_t ws_size,
                              hipStream_t stream) {
    const int* edge = (const int*)d_in[0];
    const float* x0 = (const float*)d_in[1];
    const float* W1 = (const float*)d_in[2];
    const float* b1 = (const float*)d_in[3];
    const float* W2 = (const float*)d_in[4];
    const float* b2 = (const float*)d_in[5];
    float* out = (float*)d_out;

    int E = in_sizes[0] / 2;
    int N = in_sizes[1] / DIM;
    const int* src = edge;
    const int* dst = edge + E;

    int nb = (N + 255) / 256;  // 586 <= 1024

    // workspace layout (all 256B aligned):
    char* p = (char*)d_ws;
    auto alloc = [&](size_t bytes) {
        char* r = p;
        p += (bytes + 255) & ~(size_t)255;
        return r;
    };
    int* cnt     = (int*)alloc((size_t)N * 4);
    int* cursor  = (int*)alloc((size_t)N * 4);
    int* rowptr  = (int*)alloc((size_t)N * 4);
    int* bsum    = (int*)alloc(1024 * 4);
    float* dinv  = (float*)alloc((size_t)N * 4);
    float* hh    = (float*)alloc((size_t)N * DIM * 4);
    int* csr_src = (int*)alloc((size_t)E * 4);

    int nrow_blocks = (N + 3) / 4;

    // cnt and cursor are adjacent -> single memset covers both (padding too)
    hipMemsetAsync(cnt, 0, (size_t)((char*)rowptr - (char*)cnt), stream);

    // ---- CSR build (shared by both layers) ----
    k_hist<<<2048, 256, 0, stream>>>(dst, E, cnt);
    k_dinv<<<(N + 255) / 256, 256, 0, stream>>>(cnt, dinv, N);
    k_bsum<<<nb, 256, 0, stream>>>(cnt, N, bsum);
    k_scan_bsum<<<1, 1024, 0, stream>>>(bsum, nb);
    k_rowptr<<<nb, 256, 0, stream>>>(cnt, bsum, N, rowptr);
    k_place<<<2048, 256, 0, stream>>>(src, dst, rowptr, cursor, csr_src, E);

    // ---- layer 1 ----
    k_linear<<<nrow_blocks, 256, 0, stream>>>(x0, DIM, W1, dinv, hh, N);
    k_gather<<<nrow_blocks, 256, 0, stream>>>(rowptr, cnt, csr_src, hh, dinv, b1, out, 0, N);

    // ---- layer 2 (x1 read from out, stride 128) ----
    k_linear<<<nrow_blocks, 256, 0, stream>>>(out, 128, W2, dinv, hh, N);
    k_gather<<<nrow_blocks, 256, 0, stream>>>(rowptr, cnt, csr_src, hh, dinv, b2, out, 64, N);
}

// Round 3
// 605.094 us; speedup vs baseline: 3.4780x; 1.5238x over previous
//
#include <hip/hip_runtime.h>

#define DIM 64
#define NEG 0.01f
#define CHUNK 4096
#define NBMAX 640   // >= ceil(150000/256) = 586

// exclusive scan of in[0..n) -> out[0..n), tmp[256] scratch, 256 threads
__device__ __forceinline__ void block_exscan(int* __restrict__ in, int* __restrict__ out,
                                             int* __restrict__ tmp, int n, int tid) {
    int carry = 0;
    for (int base = 0; base < n; base += 256) {
        int i = base + tid;
        int v = (i < n) ? in[i] : 0;
        tmp[tid] = v;
        __syncthreads();
        for (int o = 1; o < 256; o <<= 1) {
            int u = (tid >= o) ? tmp[tid - o] : 0;
            __syncthreads();
            tmp[tid] += u;
            __syncthreads();
        }
        if (i < n) out[i] = carry + tmp[tid] - v;
        carry += tmp[255];
        __syncthreads();
    }
}

// --- bucket histogram: bucketCnt[d>>8] += 1, LDS-staged ---
__global__ void kA_hist(const int* __restrict__ dst, int E, int* __restrict__ bucketCnt, int nb) {
    __shared__ int h[NBMAX];
    int tid = threadIdx.x;
    for (int b = tid; b < nb; b += 256) h[b] = 0;
    __syncthreads();
    int i = blockIdx.x * 256 + tid;
    int stride = gridDim.x * 256;
    for (int e = i; e < E; e += stride) atomicAdd(&h[dst[e] >> 8], 1);
    __syncthreads();
    for (int b = tid; b < nb; b += 256) if (h[b]) atomicAdd(&bucketCnt[b], h[b]);
}

// --- scan bucket counts -> base, init cursor (1 block, 1024 threads) ---
__global__ void kA_scan(const int* __restrict__ bucketCnt, int* __restrict__ bucketBase,
                        int* __restrict__ bucketCursor, int nb) {
    __shared__ int s[1024];
    int t = threadIdx.x;
    int v = (t < nb) ? bucketCnt[t] : 0;
    s[t] = v;
    __syncthreads();
    for (int o = 1; o < 1024; o <<= 1) {
        int u = (t >= o) ? s[t - o] : 0;
        __syncthreads();
        s[t] += u;
        __syncthreads();
    }
    if (t < nb) {
        int ex = s[t] - v;
        bucketBase[t] = ex;
        bucketCursor[t] = ex;
    }
}

// --- bin edges by dst-bucket with LDS chunk sort, coalesced writes ---
__global__ void kA_bin(const int* __restrict__ src, const int* __restrict__ dst, int E,
                       int* __restrict__ bucketCursor, int2* __restrict__ binned, int nb) {
    __shared__ int bCnt[NBMAX];
    __shared__ int bBase[NBMAX];
    __shared__ int bGBase[NBMAX];
    __shared__ int tmp[256];
    __shared__ int stS[CHUNK];
    __shared__ int stD[CHUNK];
    int tid = threadIdx.x;
    int e0 = blockIdx.x * CHUNK;
    int nE = min(CHUNK, E - e0);

    for (int b = tid; b < nb; b += 256) bCnt[b] = 0;
    __syncthreads();
    for (int i = tid; i < nE; i += 256) atomicAdd(&bCnt[dst[e0 + i] >> 8], 1);
    __syncthreads();
    block_exscan(bCnt, bBase, tmp, nb, tid);
    // allocate global space per bucket; reset bCnt as local cursor
    for (int b = tid; b < nb; b += 256) {
        int c = bCnt[b];
        if (c) bGBase[b] = atomicAdd(&bucketCursor[b], c);
        bCnt[b] = 0;
    }
    __syncthreads();
    // stage sorted-by-bucket into LDS
    for (int i = tid; i < nE; i += 256) {
        int s = src[e0 + i];
        int d = dst[e0 + i];
        int b = d >> 8;
        int r = atomicAdd(&bCnt[b], 1);
        int p = bBase[b] + r;
        stS[p] = s;
        stD[p] = d;
    }
    __syncthreads();
    // coalesced-run write-out
    for (int i = tid; i < nE; i += 256) {
        int d = stD[i];
        int b = d >> 8;
        int gp = bGBase[b] + (i - bBase[b]);
        binned[gp] = make_int2(stS[i], d);
    }
}

// --- per-bucket place: counts, rowptr, dinv, csr_src (1 block / bucket) ---
__global__ void kB_place(const int2* __restrict__ binned, const int* __restrict__ bucketBase,
                         const int* __restrict__ bucketCnt, int* __restrict__ cnt,
                         int* __restrict__ rowptr, float* __restrict__ dinv,
                         int* __restrict__ csr_src, int N) {
    __shared__ int nodeCnt[256];
    __shared__ int nodeOff[256];
    __shared__ int tmp[256];
    int tid = threadIdx.x;
    int b = blockIdx.x;
    int base = bucketBase[b];
    int cntE = bucketCnt[b];
    int node0 = b << 8;

    nodeCnt[tid] = 0;
    __syncthreads();
    for (int e = tid; e < cntE; e += 256) {
        int2 ed = binned[base + e];
        atomicAdd(&nodeCnt[ed.y - node0], 1);
    }
    __syncthreads();
    int myc = nodeCnt[tid];
    block_exscan(nodeCnt, nodeOff, tmp, 256, tid);
    int node = node0 + tid;
    if (node < N) {
        cnt[node] = myc;
        rowptr[node] = base + nodeOff[tid];
        dinv[node] = rsqrtf((float)myc + 1.0f);
    }
    __syncthreads();
    // nodeOff doubles as running cursor (absolute-within-bucket)
    for (int e = tid; e < cntE; e += 256) {
        int2 ed = binned[base + e];
        int r = atomicAdd(&nodeOff[ed.y - node0], 1);
        csr_src[base + r] = ed.x;
    }
}

// --- hh = (x @ W) * dinv[row] ---
__global__ void k_linear(const float* __restrict__ x, int xstride,
                         const float* __restrict__ W, const float* __restrict__ dinv,
                         float* __restrict__ hh, int N) {
    __shared__ float Ws[DIM][DIM];
    int t = threadIdx.x;
#pragma unroll
    for (int k = 0; k < 16; ++k) {
        int idx = t + k * 256;
        Ws[idx >> 6][idx & 63] = W[idx];
    }
    __syncthreads();
    int row = blockIdx.x * 4 + (t >> 6);
    int col = t & 63;
    if (row >= N) return;
    const float* xr = x + (size_t)row * xstride;
    float acc = 0.f;
#pragma unroll
    for (int k = 0; k < DIM; ++k) acc = fmaf(xr[k], Ws[k][col], acc);
    hh[(size_t)row * DIM + col] = acc * dinv[row];
}

// --- gather: out[d] = leaky( dinv[d]*(hh[d] + sum hh[src]) + b ), one wave/node ---
__global__ void k_gather(const int* __restrict__ rowptr, const int* __restrict__ cnt,
                         const int* __restrict__ csr_src, const float* __restrict__ hh,
                         const float* __restrict__ dinv, const float* __restrict__ bias,
                         float* __restrict__ out, int colOff, int N) {
    int node = blockIdx.x * (blockDim.x >> 6) + (threadIdx.x >> 6);
    int lane = threadIdx.x & 63;
    if (node >= N) return;
    int beg = rowptr[node];
    int end = beg + cnt[node];
    float acc = hh[(size_t)node * DIM + lane];  // self-loop (hh = h*dinv)
    int k = beg;
    for (; k + 3 < end; k += 4) {
        int s0 = csr_src[k], s1 = csr_src[k + 1], s2 = csr_src[k + 2], s3 = csr_src[k + 3];
        float v0 = hh[(size_t)s0 * DIM + lane];
        float v1 = hh[(size_t)s1 * DIM + lane];
        float v2 = hh[(size_t)s2 * DIM + lane];
        float v3 = hh[(size_t)s3 * DIM + lane];
        acc += (v0 + v1) + (v2 + v3);
    }
    for (; k < end; ++k) acc += hh[(size_t)csr_src[k] * DIM + lane];
    float v = acc * dinv[node] + bias[lane];
    out[(size_t)node * 128 + colOff + lane] = v > 0.f ? v : v * NEG;
}

extern "C" void kernel_launch(void* const* d_in, const int* in_sizes, int n_in,
                              void* d_out, int out_size, void* d_ws, size_t ws_size,
                              hipStream_t stream) {
    const int* edge = (const int*)d_in[0];
    const float* x0 = (const float*)d_in[1];
    const float* W1 = (const float*)d_in[2];
    const float* b1 = (const float*)d_in[3];
    const float* W2 = (const float*)d_in[4];
    const float* b2 = (const float*)d_in[5];
    float* out = (float*)d_out;

    int E = in_sizes[0] / 2;
    int N = in_sizes[1] / DIM;
    const int* src = edge;
    const int* dst = edge + E;
    int nb = (N + 255) >> 8;  // buckets of 256 nodes

    // workspace layout
    char* p = (char*)d_ws;
    auto alloc = [&](size_t bytes) {
        char* r = p;
        p += (bytes + 255) & ~(size_t)255;
        return r;
    };
    int* bucketCnt    = (int*)alloc((size_t)nb * 4);
    int* bucketBase   = (int*)alloc((size_t)nb * 4);
    int* bucketCursor = (int*)alloc((size_t)nb * 4);
    int* cnt          = (int*)alloc((size_t)N * 4);
    int* rowptr       = (int*)alloc((size_t)N * 4);
    float* dinv       = (float*)alloc((size_t)N * 4);
    int* csr_src      = (int*)alloc((size_t)E * 4);
    size_t bigBytes = (size_t)E * 8 > (size_t)N * DIM * 4 ? (size_t)E * 8 : (size_t)N * DIM * 4;
    char* big         = alloc(bigBytes);
    int2* binned = (int2*)big;   // consumed by kB_place...
    float* hh    = (float*)big;  // ...then reused as hh by k_linear

    int nrow_blocks = (N + 3) / 4;
    int nbin_blocks = (E + CHUNK - 1) / CHUNK;

    hipMemsetAsync(bucketCnt, 0, (size_t)nb * 4, stream);

    // ---- CSR build via two-level binning ----
    kA_hist<<<512, 256, 0, stream>>>(dst, E, bucketCnt, nb);
    kA_scan<<<1, 1024, 0, stream>>>(bucketCnt, bucketBase, bucketCursor, nb);
    kA_bin<<<nbin_blocks, 256, 0, stream>>>(src, dst, E, bucketCursor, binned, nb);
    kB_place<<<nb, 256, 0, stream>>>(binned, bucketBase, bucketCnt, cnt, rowptr, dinv, csr_src, N);

    // ---- layer 1 ----
    k_linear<<<nrow_blocks, 256, 0, stream>>>(x0, DIM, W1, dinv, hh, N);
    k_gather<<<nrow_blocks, 256, 0, stream>>>(rowptr, cnt, csr_src, hh, dinv, b1, out, 0, N);

    // ---- layer 2 (x1 read from out, stride 128) ----
    k_linear<<<nrow_blocks, 256, 0, stream>>>(out, 128, W2, dinv, hh, N);
    k_gather<<<nrow_blocks, 256, 0, stream>>>(rowptr, cnt, csr_src, hh, dinv, b2, out, 64, N);
}

// Round 4
// 528.673 us; speedup vs baseline: 3.9807x; 1.1446x over previous
//
#include <hip/hip_runtime.h>
#include <hip/hip_bf16.h>

#define DIM 64
#define NEG 0.01f
#define CHUNK 4096
#define NBMAX 640   // >= ceil(150000/256) = 586

// exclusive scan of in[0..n) -> out[0..n), tmp[256] scratch, 256 threads
__device__ __forceinline__ void block_exscan(int* __restrict__ in, int* __restrict__ out,
                                             int* __restrict__ tmp, int n, int tid) {
    int carry = 0;
    for (int base = 0; base < n; base += 256) {
        int i = base + tid;
        int v = (i < n) ? in[i] : 0;
        tmp[tid] = v;
        __syncthreads();
        for (int o = 1; o < 256; o <<= 1) {
            int u = (tid >= o) ? tmp[tid - o] : 0;
            __syncthreads();
            tmp[tid] += u;
            __syncthreads();
        }
        if (i < n) out[i] = carry + tmp[tid] - v;
        carry += tmp[255];
        __syncthreads();
    }
}

__device__ __forceinline__ float bf2f(unsigned short u) {
    return __uint_as_float(((unsigned int)u) << 16);
}

// --- bucket histogram: bucketCnt[d>>8] += 1, LDS-staged ---
__global__ void kA_hist(const int* __restrict__ dst, int E, int* __restrict__ bucketCnt, int nb) {
    __shared__ int h[NBMAX];
    int tid = threadIdx.x;
    for (int b = tid; b < nb; b += 256) h[b] = 0;
    __syncthreads();
    int i = blockIdx.x * 256 + tid;
    int stride = gridDim.x * 256;
    for (int e = i; e < E; e += stride) atomicAdd(&h[dst[e] >> 8], 1);
    __syncthreads();
    for (int b = tid; b < nb; b += 256) if (h[b]) atomicAdd(&bucketCnt[b], h[b]);
}

// --- scan bucket counts -> base, init cursor (1 block, 1024 threads) ---
__global__ void kA_scan(const int* __restrict__ bucketCnt, int* __restrict__ bucketBase,
                        int* __restrict__ bucketCursor, int nb) {
    __shared__ int s[1024];
    int t = threadIdx.x;
    int v = (t < nb) ? bucketCnt[t] : 0;
    s[t] = v;
    __syncthreads();
    for (int o = 1; o < 1024; o <<= 1) {
        int u = (t >= o) ? s[t - o] : 0;
        __syncthreads();
        s[t] += u;
        __syncthreads();
    }
    if (t < nb) {
        int ex = s[t] - v;
        bucketBase[t] = ex;
        bucketCursor[t] = ex;
    }
}

// --- bin edges by dst-bucket, packed (dlow<<24 | src), LDS chunk sort ---
__global__ void kA_bin(const int* __restrict__ src, const int* __restrict__ dst, int E,
                       int* __restrict__ bucketCursor, int* __restrict__ binned, int nb) {
    __shared__ int bCnt[NBMAX];
    __shared__ int bBase[NBMAX];
    __shared__ int bGBase[NBMAX];
    __shared__ int tmp[256];
    __shared__ int stP[CHUNK];
    __shared__ unsigned short stB[CHUNK];
    int tid = threadIdx.x;
    int e0 = blockIdx.x * CHUNK;
    int nE = min(CHUNK, E - e0);

    for (int b = tid; b < nb; b += 256) bCnt[b] = 0;
    __syncthreads();
    for (int i = tid; i < nE; i += 256) atomicAdd(&bCnt[dst[e0 + i] >> 8], 1);
    __syncthreads();
    block_exscan(bCnt, bBase, tmp, nb, tid);
    for (int b = tid; b < nb; b += 256) {
        int c = bCnt[b];
        if (c) bGBase[b] = atomicAdd(&bucketCursor[b], c);
        bCnt[b] = 0;
    }
    __syncthreads();
    for (int i = tid; i < nE; i += 256) {
        int s = src[e0 + i];
        int d = dst[e0 + i];
        int b = d >> 8;
        int r = atomicAdd(&bCnt[b], 1);
        int p = bBase[b] + r;
        stP[p] = ((d & 255) << 24) | s;
        stB[p] = (unsigned short)b;
    }
    __syncthreads();
    for (int i = tid; i < nE; i += 256) {
        int b = stB[i];
        int gp = bGBase[b] + (i - bBase[b]);
        binned[gp] = stP[i];
    }
}

// --- per-bucket place: counts, rowptr, dinv, csr_src (1 block / bucket) ---
__global__ void kB_place(const int* __restrict__ binned, const int* __restrict__ bucketBase,
                         const int* __restrict__ bucketCnt, int* __restrict__ cnt,
                         int* __restrict__ rowptr, float* __restrict__ dinv,
                         int* __restrict__ csr_src, int N) {
    __shared__ int nodeCnt[256];
    __shared__ int nodeOff[256];
    __shared__ int tmp[256];
    int tid = threadIdx.x;
    int b = blockIdx.x;
    int base = bucketBase[b];
    int cntE = bucketCnt[b];
    int node0 = b << 8;

    nodeCnt[tid] = 0;
    __syncthreads();
    for (int e = tid; e < cntE; e += 256) {
        unsigned int p = (unsigned int)binned[base + e];
        atomicAdd(&nodeCnt[p >> 24], 1);
    }
    __syncthreads();
    int myc = nodeCnt[tid];
    block_exscan(nodeCnt, nodeOff, tmp, 256, tid);
    int node = node0 + tid;
    if (node < N) {
        cnt[node] = myc;
        rowptr[node] = base + nodeOff[tid];
        dinv[node] = rsqrtf((float)myc + 1.0f);
    }
    __syncthreads();
    for (int e = tid; e < cntE; e += 256) {
        unsigned int p = (unsigned int)binned[base + e];
        int r = atomicAdd(&nodeOff[p >> 24], 1);
        csr_src[base + r] = (int)(p & 0xFFFFFF);
    }
}

// --- hh(bf16) = (x @ W) * dinv[row] ---
__global__ void k_linear(const float* __restrict__ x, int xstride,
                         const float* __restrict__ W, const float* __restrict__ dinv,
                         __hip_bfloat16* __restrict__ hh, int N) {
    __shared__ float Ws[DIM][DIM];
    int t = threadIdx.x;
#pragma unroll
    for (int k = 0; k < 16; ++k) {
        int idx = t + k * 256;
        Ws[idx >> 6][idx & 63] = W[idx];
    }
    __syncthreads();
    int row = blockIdx.x * 4 + (t >> 6);
    int col = t & 63;
    if (row >= N) return;
    const float* xr = x + (size_t)row * xstride;
    float acc = 0.f;
#pragma unroll
    for (int k = 0; k < DIM; ++k) acc = fmaf(xr[k], Ws[k][col], acc);
    hh[(size_t)row * DIM + col] = __float2bfloat16(acc * dinv[row]);
}

// --- gather: out[d] = leaky( dinv[d]*(hh[d] + sum hh[src]) + b ), one wave/node ---
__global__ void k_gather(const int* __restrict__ rowptr, const int* __restrict__ cnt,
                         const int* __restrict__ csr_src, const unsigned short* __restrict__ hh,
                         const float* __restrict__ dinv, const float* __restrict__ bias,
                         float* __restrict__ out, int colOff, int N) {
    int node = blockIdx.x * (blockDim.x >> 6) + (threadIdx.x >> 6);
    int lane = threadIdx.x & 63;
    if (node >= N) return;
    int beg = rowptr[node];
    int end = beg + cnt[node];
    float acc = bf2f(hh[(size_t)node * DIM + lane]);  // self-loop (hh = h*dinv)
    int k = beg;
    for (; k + 7 < end; k += 8) {
        int s0 = csr_src[k],     s1 = csr_src[k + 1], s2 = csr_src[k + 2], s3 = csr_src[k + 3];
        int s4 = csr_src[k + 4], s5 = csr_src[k + 5], s6 = csr_src[k + 6], s7 = csr_src[k + 7];
        unsigned short u0 = hh[(size_t)s0 * DIM + lane];
        unsigned short u1 = hh[(size_t)s1 * DIM + lane];
        unsigned short u2 = hh[(size_t)s2 * DIM + lane];
        unsigned short u3 = hh[(size_t)s3 * DIM + lane];
        unsigned short u4 = hh[(size_t)s4 * DIM + lane];
        unsigned short u5 = hh[(size_t)s5 * DIM + lane];
        unsigned short u6 = hh[(size_t)s6 * DIM + lane];
        unsigned short u7 = hh[(size_t)s7 * DIM + lane];
        acc += ((bf2f(u0) + bf2f(u1)) + (bf2f(u2) + bf2f(u3))) +
               ((bf2f(u4) + bf2f(u5)) + (bf2f(u6) + bf2f(u7)));
    }
    for (; k < end; ++k) acc += bf2f(hh[(size_t)csr_src[k] * DIM + lane]);
    float v = acc * dinv[node] + bias[lane];
    out[(size_t)node * 128 + colOff + lane] = v > 0.f ? v : v * NEG;
}

extern "C" void kernel_launch(void* const* d_in, const int* in_sizes, int n_in,
                              void* d_out, int out_size, void* d_ws, size_t ws_size,
                              hipStream_t stream) {
    const int* edge = (const int*)d_in[0];
    const float* x0 = (const float*)d_in[1];
    const float* W1 = (const float*)d_in[2];
    const float* b1 = (const float*)d_in[3];
    const float* W2 = (const float*)d_in[4];
    const float* b2 = (const float*)d_in[5];
    float* out = (float*)d_out;

    int E = in_sizes[0] / 2;
    int N = in_sizes[1] / DIM;
    const int* src = edge;
    const int* dst = edge + E;
    int nb = (N + 255) >> 8;

    char* p = (char*)d_ws;
    auto alloc = [&](size_t bytes) {
        char* r = p;
        p += (bytes + 255) & ~(size_t)255;
        return r;
    };
    int* bucketCnt    = (int*)alloc((size_t)nb * 4);
    int* bucketBase   = (int*)alloc((size_t)nb * 4);
    int* bucketCursor = (int*)alloc((size_t)nb * 4);
    int* cnt          = (int*)alloc((size_t)N * 4);
    int* rowptr       = (int*)alloc((size_t)N * 4);
    float* dinv       = (float*)alloc((size_t)N * 4);
    int* csr_src      = (int*)alloc((size_t)E * 4);
    size_t bigBytes = (size_t)E * 4 > (size_t)N * DIM * 2 ? (size_t)E * 4 : (size_t)N * DIM * 2;
    char* big         = alloc(bigBytes);
    int* binned = (int*)big;                    // consumed by kB_place...
    __hip_bfloat16* hh = (__hip_bfloat16*)big;  // ...then reused as hh

    int nrow_blocks = (N + 3) / 4;
    int nbin_blocks = (E + CHUNK - 1) / CHUNK;

    hipMemsetAsync(bucketCnt, 0, (size_t)nb * 4, stream);

    // ---- CSR build via two-level binning ----
    kA_hist<<<512, 256, 0, stream>>>(dst, E, bucketCnt, nb);
    kA_scan<<<1, 1024, 0, stream>>>(bucketCnt, bucketBase, bucketCursor, nb);
    kA_bin<<<nbin_blocks, 256, 0, stream>>>(src, dst, E, bucketCursor, binned, nb);
    kB_place<<<nb, 256, 0, stream>>>(binned, bucketBase, bucketCnt, cnt, rowptr, dinv, csr_src, N);

    // ---- layer 1 ----
    k_linear<<<nrow_blocks, 256, 0, stream>>>(x0, DIM, W1, dinv, hh, N);
    k_gather<<<nrow_blocks, 256, 0, stream>>>(rowptr, cnt, csr_src, (const unsigned short*)hh, dinv, b1, out, 0, N);

    // ---- layer 2 (x1 read from out, stride 128) ----
    k_linear<<<nrow_blocks, 256, 0, stream>>>(out, 128, W2, dinv, hh, N);
    k_gather<<<nrow_blocks, 256, 0, stream>>>(rowptr, cnt, csr_src, (const unsigned short*)hh, dinv, b2, out, 64, N);
}